// Round 1
// baseline (476.153 us; speedup 1.0000x reference)
//
#include <hip/hip_runtime.h>
#include <hip/hip_bf16.h>
#include <math.h>

#define NB 64        // B
#define NH 8         // H
#define DKH 32       // DK
#define NE 65536     // E
#define ND 256       // N2 (=K dim of all GEMMs)
#define CAP 32       // per-thread LDS score slots

// ---------------- small row GEMM: Y[b,j] = bias[j] + sum_k X[b,k]*W[j,k]
__global__ __launch_bounds__(256) void rowgemm_k(const float* __restrict__ X,
    const float* __restrict__ W, const float* __restrict__ bias,
    float* __restrict__ Y)
{
  __shared__ float xs[ND];
  const int b = blockIdx.x;
  const int j = threadIdx.x;
  xs[j] = X[(size_t)b * ND + j];
  __syncthreads();
  float acc = bias[j];
  const float4* wp = (const float4*)(W + (size_t)j * ND);
  #pragma unroll 8
  for (int k4 = 0; k4 < ND / 4; ++k4) {
    float4 w = wp[k4];
    float4 x = *(const float4*)&xs[k4 * 4];
    acc = fmaf(x.x, w.x, acc);
    acc = fmaf(x.y, w.y, acc);
    acc = fmaf(x.z, w.z, acc);
    acc = fmaf(x.w, w.w, acc);
  }
  Y[(size_t)b * ND + j] = acc;
}

// ---------------- 128x128 tiled f32 GEMM: C[m,n] = bias[n] + sum_k X[m,k]*W[n,k]
// X: [M,256] row-major, W: [256,256] row-major (torch Linear weight), C: [M,256]
__global__ __launch_bounds__(256) void gemm_proj_k(const float* __restrict__ X,
    const float* __restrict__ W, const float* __restrict__ bias,
    float* __restrict__ C)
{
  __shared__ float As[16][132];
  __shared__ float Bs[16][132];
  const int tid = threadIdx.x;
  const int n0 = blockIdx.x * 128;
  const int m0 = blockIdx.y * 128;
  const int tx = tid & 15, ty = tid >> 4;
  const int lrow = tid >> 2;           // 0..63
  const int lc4 = (tid & 3) << 2;      // 0,4,8,12

  float acc[8][8];
  #pragma unroll
  for (int i = 0; i < 8; ++i)
    #pragma unroll
    for (int jj = 0; jj < 8; ++jj) acc[i][jj] = 0.f;

  for (int kt = 0; kt < ND; kt += 16) {
    #pragma unroll
    for (int half = 0; half < 2; ++half) {
      const int r = lrow + half * 64;
      float4 av = *(const float4*)(X + (size_t)(m0 + r) * ND + kt + lc4);
      As[lc4 + 0][r] = av.x; As[lc4 + 1][r] = av.y;
      As[lc4 + 2][r] = av.z; As[lc4 + 3][r] = av.w;
      float4 bv = *(const float4*)(W + (size_t)(n0 + r) * ND + kt + lc4);
      Bs[lc4 + 0][r] = bv.x; Bs[lc4 + 1][r] = bv.y;
      Bs[lc4 + 2][r] = bv.z; Bs[lc4 + 3][r] = bv.w;
    }
    __syncthreads();
    #pragma unroll
    for (int kk = 0; kk < 16; ++kk) {
      float4 a0 = *(const float4*)&As[kk][ty * 8];
      float4 a1 = *(const float4*)&As[kk][ty * 8 + 4];
      float4 b0 = *(const float4*)&Bs[kk][tx * 8];
      float4 b1 = *(const float4*)&Bs[kk][tx * 8 + 4];
      float a[8] = {a0.x, a0.y, a0.z, a0.w, a1.x, a1.y, a1.z, a1.w};
      float bb[8] = {b0.x, b0.y, b0.z, b0.w, b1.x, b1.y, b1.z, b1.w};
      #pragma unroll
      for (int i = 0; i < 8; ++i)
        #pragma unroll
        for (int jj = 0; jj < 8; ++jj)
          acc[i][jj] = fmaf(a[i], bb[jj], acc[i][jj]);
    }
    __syncthreads();
  }

  #pragma unroll
  for (int i = 0; i < 8; ++i) {
    const int mrow = m0 + ty * 8 + i;
    float* cp = C + (size_t)mrow * ND + n0 + tx * 8;
    float4 o0, o1;
    o0.x = acc[i][0] + bias[n0 + tx * 8 + 0];
    o0.y = acc[i][1] + bias[n0 + tx * 8 + 1];
    o0.z = acc[i][2] + bias[n0 + tx * 8 + 2];
    o0.w = acc[i][3] + bias[n0 + tx * 8 + 3];
    o1.x = acc[i][4] + bias[n0 + tx * 8 + 4];
    o1.y = acc[i][5] + bias[n0 + tx * 8 + 5];
    o1.z = acc[i][6] + bias[n0 + tx * 8 + 6];
    o1.w = acc[i][7] + bias[n0 + tx * 8 + 7];
    *(float4*)cp = o0;
    *(float4*)(cp + 4) = o1;
  }
}

// ---------------- segment attention
__device__ __forceinline__ float dot_qk(const float* __restrict__ kp, const float qr[32]) {
  float s = 0.f;
  const float4* kp4 = (const float4*)kp;
  #pragma unroll
  for (int j = 0; j < 8; ++j) {
    float4 kv = kp4[j];
    s = fmaf(qr[4 * j + 0], kv.x, s);
    s = fmaf(qr[4 * j + 1], kv.y, s);
    s = fmaf(qr[4 * j + 2], kv.z, s);
    s = fmaf(qr[4 * j + 3], kv.w, s);
  }
  return s;
}

__global__ __launch_bounds__(256) void attn_k(const float* __restrict__ q_ws,
    const float* __restrict__ k_ws, const float* __restrict__ v_ws,
    const int* __restrict__ batch, float* __restrict__ attn_out,
    float* __restrict__ out_ws)
{
  __shared__ float s_sc[CAP][256];
  __shared__ float s_m[4], s_l[4];
  __shared__ float s_red[4][DKH];
  __shared__ float s_ml[2];

  const int tid = threadIdx.x;
  const int hb = blockIdx.x;        // h*64 + b
  const int h = hb >> 6;
  const int b = hb & 63;
  const int wid = tid >> 6, lane = tid & 63;

  float qr[32];
  {
    const float4* qp = (const float4*)(q_ws + (size_t)b * ND + h * DKH);
    #pragma unroll
    for (int j = 0; j < 8; ++j) {
      float4 t = qp[j];
      qr[4 * j + 0] = t.x; qr[4 * j + 1] = t.y;
      qr[4 * j + 2] = t.z; qr[4 * j + 3] = t.w;
    }
  }

  float* __restrict__ arow = attn_out + (size_t)hb * NE;

  // ---- pass 1: online (m,l) + cache scores in LDS
  float m = -INFINITY, l = 0.f;
  int cnt = 0;
  for (int it = 0; it < NE / 1024; ++it) {
    const int e0 = it * 1024 + tid * 4;
    const int4 bt = *(const int4*)(batch + e0);
    const int bts[4] = {bt.x, bt.y, bt.z, bt.w};
    #pragma unroll
    for (int u = 0; u < 4; ++u) {
      if (bts[u] == b) {
        float s = dot_qk(k_ws + (size_t)(e0 + u) * ND + h * DKH, qr);
        float mn = fmaxf(m, s);
        l = l * __expf(m - mn) + __expf(s - mn);
        m = mn;
        if (cnt < CAP) s_sc[cnt][tid] = s;
        ++cnt;
      }
    }
  }

  // ---- block reduce (m,l) with -inf guards
  #pragma unroll
  for (int off = 32; off > 0; off >>= 1) {
    float mo = __shfl_xor(m, off);
    float lo = __shfl_xor(l, off);
    float mn = fmaxf(m, mo);
    if (mn == -INFINITY) { l = 0.f; }
    else { l = l * __expf(m - mn) + lo * __expf(mo - mn); }
    m = mn;
  }
  if (lane == 0) { s_m[wid] = m; s_l[wid] = l; }
  __syncthreads();
  if (tid == 0) {
    float mm = -INFINITY, ll = 0.f;
    #pragma unroll
    for (int w = 0; w < 4; ++w) {
      float mo = s_m[w], lo = s_l[w];
      float mn = fmaxf(mm, mo);
      if (mn == -INFINITY) { ll = 0.f; }
      else { ll = ll * __expf(mm - mn) + lo * __expf(mo - mn); }
      mm = mn;
    }
    s_ml[0] = mm;
    s_ml[1] = (ll > 0.f) ? 1.f / ll : 0.f;
  }
  __syncthreads();
  const float m_all = s_ml[0];
  const float inv = s_ml[1];

  // ---- pass 2: write attn densely, accumulate PV
  float oa[32];
  #pragma unroll
  for (int d = 0; d < 32; ++d) oa[d] = 0.f;
  int c = 0;
  for (int it = 0; it < NE / 1024; ++it) {
    const int e0 = it * 1024 + tid * 4;
    const int4 bt = *(const int4*)(batch + e0);
    const int bts[4] = {bt.x, bt.y, bt.z, bt.w};
    float av[4];
    #pragma unroll
    for (int u = 0; u < 4; ++u) {
      float a = 0.f;
      if (bts[u] == b) {
        float s = (c < CAP) ? s_sc[c][tid]
                            : dot_qk(k_ws + (size_t)(e0 + u) * ND + h * DKH, qr);
        ++c;
        a = __expf(s - m_all) * inv;
        const float4* vp = (const float4*)(v_ws + (size_t)(e0 + u) * ND + h * DKH);
        #pragma unroll
        for (int j = 0; j < 8; ++j) {
          float4 vv = vp[j];
          oa[4 * j + 0] = fmaf(a, vv.x, oa[4 * j + 0]);
          oa[4 * j + 1] = fmaf(a, vv.y, oa[4 * j + 1]);
          oa[4 * j + 2] = fmaf(a, vv.z, oa[4 * j + 2]);
          oa[4 * j + 3] = fmaf(a, vv.w, oa[4 * j + 3]);
        }
      }
      av[u] = a;
    }
    float4 ao;
    ao.x = av[0]; ao.y = av[1]; ao.z = av[2]; ao.w = av[3];
    *(float4*)(arow + e0) = ao;
  }

  // ---- reduce oa[32] across block -> out_ws[b*256 + h*32 + d]
  #pragma unroll
  for (int d = 0; d < 32; ++d) {
    #pragma unroll
    for (int off = 32; off > 0; off >>= 1)
      oa[d] += __shfl_down(oa[d], off);
  }
  if (lane == 0) {
    #pragma unroll
    for (int d = 0; d < 32; ++d) s_red[wid][d] = oa[d];
  }
  __syncthreads();
  if (tid < 32) {
    float v = s_red[0][tid] + s_red[1][tid] + s_red[2][tid] + s_red[3][tid];
    out_ws[(size_t)b * ND + h * DKH + tid] = v;
  }
}

extern "C" void kernel_launch(void* const* d_in, const int* in_sizes, int n_in,
                              void* d_out, int out_size, void* d_ws, size_t ws_size,
                              hipStream_t stream)
{
  const float* gq   = (const float*)d_in[0];
  const float* lk   = (const float*)d_in[1];
  const float* lv   = (const float*)d_in[2];
  const int*  batch = (const int*)d_in[3];
  const float* Wq = (const float*)d_in[4];
  const float* bq = (const float*)d_in[5];
  const float* Wk = (const float*)d_in[6];
  const float* bk = (const float*)d_in[7];
  const float* Wv = (const float*)d_in[8];
  const float* bv = (const float*)d_in[9];
  const float* Wo = (const float*)d_in[10];
  const float* bo = (const float*)d_in[11];

  float* xout = (float*)d_out;                          // [64,256]
  float* attn_out = xout + (size_t)NB * ND;             // [H,B,E]

  float* q_ws   = (float*)d_ws;                         // 64*256
  float* out_ws = q_ws + (size_t)NB * ND;               // 64*256
  float* k_ws   = out_ws + (size_t)NB * ND;             // E*256
  float* v_ws   = k_ws + (size_t)NE * ND;               // E*256

  rowgemm_k<<<NB, ND, 0, stream>>>(gq, Wq, bq, q_ws);
  gemm_proj_k<<<dim3(2, NE / 128), 256, 0, stream>>>(lk, Wk, bk, k_ws);
  gemm_proj_k<<<dim3(2, NE / 128), 256, 0, stream>>>(lv, Wv, bv, v_ws);
  attn_k<<<NH * NB, 256, 0, stream>>>(q_ws, k_ws, v_ws, batch, attn_out, out_ws);
  rowgemm_k<<<NB, ND, 0, stream>>>(out_ws, Wo, bo, xout);
}

// Round 2
// 340.638 us; speedup vs baseline: 1.3978x; 1.3978x over previous
//
#include <hip/hip_runtime.h>
#include <hip/hip_bf16.h>
#include <math.h>

#define NB 64        // B
#define NH 8         // H
#define DKH 32       // DK
#define NE 65536     // E
#define ND 256       // N2 (=K dim of all GEMMs)
#define IDX_STRIDE 2048

// ---------------- small row GEMM: Y[b,j] = bias[j] + sum_k X[b,k]*W[j,k]
__global__ __launch_bounds__(256) void rowgemm_k(const float* __restrict__ X,
    const float* __restrict__ W, const float* __restrict__ bias,
    float* __restrict__ Y)
{
  __shared__ float xs[ND];
  const int b = blockIdx.x;
  const int j = threadIdx.x;
  xs[j] = X[(size_t)b * ND + j];
  __syncthreads();
  float acc = bias[j];
  const float4* wp = (const float4*)(W + (size_t)j * ND);
  #pragma unroll 8
  for (int k4 = 0; k4 < ND / 4; ++k4) {
    float4 w = wp[k4];
    float4 x = *(const float4*)&xs[k4 * 4];
    acc = fmaf(x.x, w.x, acc);
    acc = fmaf(x.y, w.y, acc);
    acc = fmaf(x.z, w.z, acc);
    acc = fmaf(x.w, w.w, acc);
  }
  Y[(size_t)b * ND + j] = acc;
}

// ---------------- 128x128 tiled f32 GEMM: C[m,n] = bias[n] + sum_k X[m,k]*W[n,k]
__global__ __launch_bounds__(256) void gemm_proj_k(const float* __restrict__ X,
    const float* __restrict__ W, const float* __restrict__ bias,
    float* __restrict__ C)
{
  __shared__ float As[16][132];
  __shared__ float Bs[16][132];
  const int tid = threadIdx.x;
  const int n0 = blockIdx.x * 128;
  const int m0 = blockIdx.y * 128;
  const int tx = tid & 15, ty = tid >> 4;
  const int lrow = tid >> 2;           // 0..63
  const int lc4 = (tid & 3) << 2;      // 0,4,8,12

  float acc[8][8];
  #pragma unroll
  for (int i = 0; i < 8; ++i)
    #pragma unroll
    for (int jj = 0; jj < 8; ++jj) acc[i][jj] = 0.f;

  for (int kt = 0; kt < ND; kt += 16) {
    #pragma unroll
    for (int half = 0; half < 2; ++half) {
      const int r = lrow + half * 64;
      float4 av = *(const float4*)(X + (size_t)(m0 + r) * ND + kt + lc4);
      As[lc4 + 0][r] = av.x; As[lc4 + 1][r] = av.y;
      As[lc4 + 2][r] = av.z; As[lc4 + 3][r] = av.w;
      float4 bv = *(const float4*)(W + (size_t)(n0 + r) * ND + kt + lc4);
      Bs[lc4 + 0][r] = bv.x; Bs[lc4 + 1][r] = bv.y;
      Bs[lc4 + 2][r] = bv.z; Bs[lc4 + 3][r] = bv.w;
    }
    __syncthreads();
    #pragma unroll
    for (int kk = 0; kk < 16; ++kk) {
      float4 a0 = *(const float4*)&As[kk][ty * 8];
      float4 a1 = *(const float4*)&As[kk][ty * 8 + 4];
      float4 b0 = *(const float4*)&Bs[kk][tx * 8];
      float4 b1 = *(const float4*)&Bs[kk][tx * 8 + 4];
      float a[8] = {a0.x, a0.y, a0.z, a0.w, a1.x, a1.y, a1.z, a1.w};
      float bb[8] = {b0.x, b0.y, b0.z, b0.w, b1.x, b1.y, b1.z, b1.w};
      #pragma unroll
      for (int i = 0; i < 8; ++i)
        #pragma unroll
        for (int jj = 0; jj < 8; ++jj)
          acc[i][jj] = fmaf(a[i], bb[jj], acc[i][jj]);
    }
    __syncthreads();
  }

  #pragma unroll
  for (int i = 0; i < 8; ++i) {
    const int mrow = m0 + ty * 8 + i;
    float* cp = C + (size_t)mrow * ND + n0 + tx * 8;
    float4 o0, o1;
    o0.x = acc[i][0] + bias[n0 + tx * 8 + 0];
    o0.y = acc[i][1] + bias[n0 + tx * 8 + 1];
    o0.z = acc[i][2] + bias[n0 + tx * 8 + 2];
    o0.w = acc[i][3] + bias[n0 + tx * 8 + 3];
    o1.x = acc[i][4] + bias[n0 + tx * 8 + 4];
    o1.y = acc[i][5] + bias[n0 + tx * 8 + 5];
    o1.z = acc[i][6] + bias[n0 + tx * 8 + 6];
    o1.w = acc[i][7] + bias[n0 + tx * 8 + 7];
    *(float4*)cp = o0;
    *(float4*)(cp + 4) = o1;
  }
}

// ---------------- stable stream-compaction: per-b index lists
__global__ __launch_bounds__(512) void bucket_k(const int* __restrict__ batch,
    int* __restrict__ idx, int* __restrict__ counts)
{
  __shared__ int wbase[8];
  __shared__ int running;
  const int b = blockIdx.x;
  const int tid = threadIdx.x;
  const int wid = tid >> 6, lane = tid & 63;
  const unsigned long long lt = (1ULL << lane) - 1ULL;
  if (tid == 0) running = 0;
  int* __restrict__ myidx = idx + b * IDX_STRIDE;

  for (int it = 0; it < NE / 2048; ++it) {
    const int e0 = it * 2048 + tid * 4;
    const int4 bt = *(const int4*)(batch + e0);
    const bool f[4] = {bt.x == b, bt.y == b, bt.z == b, bt.w == b};
    int rk[4];
    int wcnt = 0;
    #pragma unroll
    for (int u = 0; u < 4; ++u) {
      unsigned long long mk = __ballot(f[u]);
      rk[u] = wcnt + __popcll(mk & lt);
      wcnt += __popcll(mk);
    }
    __syncthreads();                 // protect wbase from previous iteration's readers
    if (lane == 0) wbase[wid] = wcnt;
    __syncthreads();
    if (tid == 0) {
      int r = running;
      #pragma unroll
      for (int w = 0; w < 8; ++w) { int c = wbase[w]; wbase[w] = r; r += c; }
      running = r;
    }
    __syncthreads();
    const int base = wbase[wid];
    #pragma unroll
    for (int u = 0; u < 4; ++u) {
      const int p = base + rk[u];
      if (f[u] && p < IDX_STRIDE) myidx[p] = e0 + u;
    }
  }
  __syncthreads();
  if (tid == 0) counts[b] = running;
}

// ---------------- segment attention over bucketized index lists
__device__ __forceinline__ float dot_qk(const float* __restrict__ kp, const float qr[32]) {
  float s = 0.f;
  const float4* kp4 = (const float4*)kp;
  #pragma unroll
  for (int j = 0; j < 8; ++j) {
    float4 kv = kp4[j];
    s = fmaf(qr[4 * j + 0], kv.x, s);
    s = fmaf(qr[4 * j + 1], kv.y, s);
    s = fmaf(qr[4 * j + 2], kv.z, s);
    s = fmaf(qr[4 * j + 3], kv.w, s);
  }
  return s;
}

__global__ __launch_bounds__(256) void attn_k(const float* __restrict__ q_ws,
    const float* __restrict__ k_ws, const float* __restrict__ v_ws,
    const int* __restrict__ idx, const int* __restrict__ counts,
    float* __restrict__ attn_out, float* __restrict__ out_ws)
{
  __shared__ float s_sc[IDX_STRIDE];
  __shared__ float s_m[4], s_l[4];
  __shared__ float s_red[4][DKH];
  __shared__ float s_ml[2];

  const int tid = threadIdx.x;
  const int hb = blockIdx.x;        // h*64 + b
  const int h = hb >> 6;
  const int b = hb & 63;
  const int wid = tid >> 6, lane = tid & 63;

  const int count = min(counts[b], IDX_STRIDE);
  const int* __restrict__ myidx = idx + b * IDX_STRIDE;

  float qr[32];
  {
    const float4* qp = (const float4*)(q_ws + (size_t)b * ND + h * DKH);
    #pragma unroll
    for (int j = 0; j < 8; ++j) {
      float4 t = qp[j];
      qr[4 * j + 0] = t.x; qr[4 * j + 1] = t.y;
      qr[4 * j + 2] = t.z; qr[4 * j + 3] = t.w;
    }
  }

  // ---- pass 1: scores (all lanes active), online (m,l), cache scores in LDS
  float m = -INFINITY, l = 0.f;
  for (int j = tid; j < count; j += 256) {
    const int e = myidx[j];
    const float s = dot_qk(k_ws + (size_t)e * ND + h * DKH, qr);
    s_sc[j] = s;
    const float mn = fmaxf(m, s);
    l = l * __expf(m - mn) + __expf(s - mn);
    m = mn;
  }

  // ---- block reduce (m,l) with -inf guards
  #pragma unroll
  for (int off = 32; off > 0; off >>= 1) {
    float mo = __shfl_xor(m, off);
    float lo = __shfl_xor(l, off);
    float mn = fmaxf(m, mo);
    if (mn == -INFINITY) { l = 0.f; }
    else { l = l * __expf(m - mn) + lo * __expf(mo - mn); }
    m = mn;
  }
  if (lane == 0) { s_m[wid] = m; s_l[wid] = l; }
  __syncthreads();
  if (tid == 0) {
    float mm = -INFINITY, ll = 0.f;
    #pragma unroll
    for (int w = 0; w < 4; ++w) {
      float mo = s_m[w], lo = s_l[w];
      float mn = fmaxf(mm, mo);
      if (mn == -INFINITY) { ll = 0.f; }
      else { ll = ll * __expf(mm - mn) + lo * __expf(mo - mn); }
      mm = mn;
    }
    s_ml[0] = mm;
    s_ml[1] = (ll > 0.f) ? 1.f / ll : 0.f;
  }
  __syncthreads();
  const float m_all = s_ml[0];
  const float inv = s_ml[1];

  // ---- pass 2a: dense zero of this (h,b) attn row (coalesced)
  float* __restrict__ arow = attn_out + (size_t)hb * NE;
  const float4 z4 = {0.f, 0.f, 0.f, 0.f};
  for (int it = 0; it < NE / 1024; ++it)
    *(float4*)(arow + it * 1024 + tid * 4) = z4;
  __syncthreads();   // compiler drains vmcnt before s_barrier -> zeros visible

  // ---- pass 2b: scatter the segment's weights (lines are L2-hot)
  for (int j = tid; j < count; j += 256)
    arow[myidx[j]] = __expf(s_sc[j] - m_all) * inv;

  // ---- pass 3: PV over the index list (all lanes active)
  float oa[32];
  #pragma unroll
  for (int d = 0; d < 32; ++d) oa[d] = 0.f;
  for (int j = tid; j < count; j += 256) {
    const int e = myidx[j];
    const float a = __expf(s_sc[j] - m_all) * inv;
    const float4* vp = (const float4*)(v_ws + (size_t)e * ND + h * DKH);
    #pragma unroll
    for (int jj = 0; jj < 8; ++jj) {
      float4 vv = vp[jj];
      oa[4 * jj + 0] = fmaf(a, vv.x, oa[4 * jj + 0]);
      oa[4 * jj + 1] = fmaf(a, vv.y, oa[4 * jj + 1]);
      oa[4 * jj + 2] = fmaf(a, vv.z, oa[4 * jj + 2]);
      oa[4 * jj + 3] = fmaf(a, vv.w, oa[4 * jj + 3]);
    }
  }

  // ---- reduce oa[32] across block -> out_ws[b*256 + h*32 + d]
  #pragma unroll
  for (int d = 0; d < 32; ++d) {
    #pragma unroll
    for (int off = 32; off > 0; off >>= 1)
      oa[d] += __shfl_down(oa[d], off);
  }
  if (lane == 0) {
    #pragma unroll
    for (int d = 0; d < 32; ++d) s_red[wid][d] = oa[d];
  }
  __syncthreads();
  if (tid < 32) {
    float v = s_red[0][tid] + s_red[1][tid] + s_red[2][tid] + s_red[3][tid];
    out_ws[(size_t)b * ND + h * DKH + tid] = v;
  }
}

extern "C" void kernel_launch(void* const* d_in, const int* in_sizes, int n_in,
                              void* d_out, int out_size, void* d_ws, size_t ws_size,
                              hipStream_t stream)
{
  const float* gq   = (const float*)d_in[0];
  const float* lk   = (const float*)d_in[1];
  const float* lv   = (const float*)d_in[2];
  const int*  batch = (const int*)d_in[3];
  const float* Wq = (const float*)d_in[4];
  const float* bq = (const float*)d_in[5];
  const float* Wk = (const float*)d_in[6];
  const float* bk = (const float*)d_in[7];
  const float* Wv = (const float*)d_in[8];
  const float* bv = (const float*)d_in[9];
  const float* Wo = (const float*)d_in[10];
  const float* bo = (const float*)d_in[11];

  float* xout = (float*)d_out;                          // [64,256]
  float* attn_out = xout + (size_t)NB * ND;             // [H,B,E]

  float* q_ws   = (float*)d_ws;                         // 64*256
  float* out_ws = q_ws + (size_t)NB * ND;               // 64*256
  float* k_ws   = out_ws + (size_t)NB * ND;             // E*256
  float* v_ws   = k_ws + (size_t)NE * ND;               // E*256
  int*   idx    = (int*)(v_ws + (size_t)NE * ND);       // 64*2048
  int*   counts = idx + (size_t)NB * IDX_STRIDE;        // 64

  rowgemm_k<<<NB, ND, 0, stream>>>(gq, Wq, bq, q_ws);
  gemm_proj_k<<<dim3(2, NE / 128), 256, 0, stream>>>(lk, Wk, bk, k_ws);
  gemm_proj_k<<<dim3(2, NE / 128), 256, 0, stream>>>(lv, Wv, bv, v_ws);
  bucket_k<<<NB, 512, 0, stream>>>(batch, idx, counts);
  attn_k<<<NH * NB, 256, 0, stream>>>(q_ws, k_ws, v_ws, idx, counts, attn_out, out_ws);
  rowgemm_k<<<NB, ND, 0, stream>>>(out_ws, Wo, bo, xout);
}

// Round 3
// 208.951 us; speedup vs baseline: 2.2788x; 1.6302x over previous
//
#include <hip/hip_runtime.h>
#include <hip/hip_bf16.h>
#include <math.h>

#define NB 64        // B
#define NH 8         // H
#define DKH 32       // DK
#define NE 65536     // E
#define ND 256       // N2 (=K dim of all GEMMs)
#define IDX_STRIDE 2048

typedef __attribute__((ext_vector_type(8))) short short8_t;
typedef __attribute__((ext_vector_type(8))) unsigned short ushort8_t;
typedef __attribute__((ext_vector_type(4))) float float4_t;

static __device__ __forceinline__ unsigned short f2bf(float f) {
  __hip_bfloat16 h = __float2bfloat16(f);
  return *reinterpret_cast<unsigned short*>(&h);
}

// ---------------- small row GEMM (f32): Y[b,j] = bias[j] + sum_k X[b,k]*W[j,k]
__global__ __launch_bounds__(256) void rowgemm_k(const float* __restrict__ X,
    const float* __restrict__ W, const float* __restrict__ bias,
    float* __restrict__ Y)
{
  __shared__ float xs[ND];
  const int b = blockIdx.x;
  const int j = threadIdx.x;
  xs[j] = X[(size_t)b * ND + j];
  __syncthreads();
  float acc = bias[j];
  const float4* wp = (const float4*)(W + (size_t)j * ND);
  #pragma unroll 8
  for (int k4 = 0; k4 < ND / 4; ++k4) {
    float4 w = wp[k4];
    float4 x = *(const float4*)&xs[k4 * 4];
    acc = fmaf(x.x, w.x, acc);
    acc = fmaf(x.y, w.y, acc);
    acc = fmaf(x.z, w.z, acc);
    acc = fmaf(x.w, w.w, acc);
  }
  Y[(size_t)b * ND + j] = acc;
}

// ---------------- bf16 MFMA GEMM: C[m,n] = bias[n] + sum_k X[m,k]*W[n,k]
// X: [65536,256] f32 row-major, W: [256,256] f32 row-major, C: [65536,256] f32.
// 128x128 tile, BK=64, 4 waves (2x2), each wave 64x64 via 4x4 mfma 16x16x32.
// Reg-staged f32->bf16 conversion into XOR-swizzled LDS (both sides swizzled).
__global__ __launch_bounds__(256) void gemm_bf16_k(const float* __restrict__ X,
    const float* __restrict__ W, const float* __restrict__ bias,
    float* __restrict__ C)
{
  __shared__ unsigned short As[128 * 64];
  __shared__ unsigned short Bs[128 * 64];

  const int tid = threadIdx.x;
  const int lane = tid & 63;
  const int wid = tid >> 6;
  const int wr = wid >> 1, wc = wid & 1;

  // XCD-aware swizzle: grid = 1024 blocks; pairs (nt=0,1) of one m-tile stay
  // adjacent on one XCD so the shared A panel is an L2 hit.
  const int bid = blockIdx.x;
  const int swz = (bid & 7) * 128 + (bid >> 3);
  const int n0 = (swz & 1) * 128;
  const int m0 = (swz >> 1) * 128;

  // staging constants: chunk c = q*256+tid covers row=c>>3, slot=c&7 (8 bf16)
  const int srow = tid >> 3;                       // + q*32
  const int sslot = (tid & 7) ^ ((tid >> 3) & 7);  // slot ^ (row&7)
  const int scol = (tid & 7) * 8;

  // fragment-read constants
  const int lr = lane & 15;
  const int lk8 = lane >> 4;                       // 0..3
  const int abase = (wr * 64 + lr) * 128;          // bytes (row*128)
  const int bbase = (wc * 64 + lr) * 128;
  const int swzk0 = (lk8 ^ (lr & 7)) * 16;
  const int swzk1 = ((lk8 + 4) ^ (lr & 7)) * 16;

  float4_t acc[4][4];
  #pragma unroll
  for (int i = 0; i < 4; ++i)
    #pragma unroll
    for (int j = 0; j < 4; ++j)
      acc[i][j] = (float4_t){0.f, 0.f, 0.f, 0.f};

  float4 sa[8], sb[8];

  // preload K-step 0
  #pragma unroll
  for (int q = 0; q < 4; ++q) {
    const int row = q * 32 + srow;
    const float* xp = X + (size_t)(m0 + row) * ND + scol;
    sa[2 * q] = *(const float4*)xp;
    sa[2 * q + 1] = *(const float4*)(xp + 4);
    const float* wp = W + (size_t)(n0 + row) * ND + scol;
    sb[2 * q] = *(const float4*)wp;
    sb[2 * q + 1] = *(const float4*)(wp + 4);
  }

  for (int ks = 0; ks < ND / 64; ++ks) {
    __syncthreads();   // previous tile's compute done; LDS free
    #pragma unroll
    for (int q = 0; q < 4; ++q) {
      ushort8_t ha, hb;
      ha[0] = f2bf(sa[2*q].x); ha[1] = f2bf(sa[2*q].y);
      ha[2] = f2bf(sa[2*q].z); ha[3] = f2bf(sa[2*q].w);
      ha[4] = f2bf(sa[2*q+1].x); ha[5] = f2bf(sa[2*q+1].y);
      ha[6] = f2bf(sa[2*q+1].z); ha[7] = f2bf(sa[2*q+1].w);
      hb[0] = f2bf(sb[2*q].x); hb[1] = f2bf(sb[2*q].y);
      hb[2] = f2bf(sb[2*q].z); hb[3] = f2bf(sb[2*q].w);
      hb[4] = f2bf(sb[2*q+1].x); hb[5] = f2bf(sb[2*q+1].y);
      hb[6] = f2bf(sb[2*q+1].z); hb[7] = f2bf(sb[2*q+1].w);
      const int off = q * 4096 + srow * 128 + sslot * 16;
      *(ushort8_t*)((char*)As + off) = ha;
      *(ushort8_t*)((char*)Bs + off) = hb;
    }
    __syncthreads();

    // issue next tile's loads (overlap with compute below)
    if (ks + 1 < ND / 64) {
      const int kt = (ks + 1) * 64;
      #pragma unroll
      for (int q = 0; q < 4; ++q) {
        const int row = q * 32 + srow;
        const float* xp = X + (size_t)(m0 + row) * ND + kt + scol;
        sa[2 * q] = *(const float4*)xp;
        sa[2 * q + 1] = *(const float4*)(xp + 4);
        const float* wp = W + (size_t)(n0 + row) * ND + kt + scol;
        sb[2 * q] = *(const float4*)wp;
        sb[2 * q + 1] = *(const float4*)(wp + 4);
      }
    }

    #pragma unroll
    for (int kk = 0; kk < 2; ++kk) {
      const int sw = kk ? swzk1 : swzk0;
      short8_t af[4], bfg[4];
      #pragma unroll
      for (int s = 0; s < 4; ++s) {
        af[s] = *(const short8_t*)((const char*)As + abase + s * 2048 + sw);
        bfg[s] = *(const short8_t*)((const char*)Bs + bbase + s * 2048 + sw);
      }
      #pragma unroll
      for (int i = 0; i < 4; ++i)
        #pragma unroll
        for (int j = 0; j < 4; ++j)
          acc[i][j] = __builtin_amdgcn_mfma_f32_16x16x32_bf16(
              af[i], bfg[j], acc[i][j], 0, 0, 0);
    }
  }

  // epilogue: D[row=(l>>4)*4+r][col=l&15] per frag (verified m89/m91 layout)
  const int crow0 = m0 + wr * 64 + (lane >> 4) * 4;
  const int ccol0 = n0 + wc * 64 + (lane & 15);
  #pragma unroll
  for (int j = 0; j < 4; ++j) {
    const int col = ccol0 + j * 16;
    const float bsv = bias[col];
    #pragma unroll
    for (int i = 0; i < 4; ++i) {
      #pragma unroll
      for (int r = 0; r < 4; ++r)
        C[(size_t)(crow0 + i * 16 + r) * ND + col] = acc[i][j][r] + bsv;
    }
  }
}

// ---------------- stable stream-compaction: per-b index lists
__global__ __launch_bounds__(512) void bucket_k(const int* __restrict__ batch,
    int* __restrict__ idx, int* __restrict__ counts)
{
  __shared__ int wbase[8];
  __shared__ int running;
  const int b = blockIdx.x;
  const int tid = threadIdx.x;
  const int wid = tid >> 6, lane = tid & 63;
  const unsigned long long lt = (1ULL << lane) - 1ULL;
  if (tid == 0) running = 0;
  int* __restrict__ myidx = idx + b * IDX_STRIDE;

  for (int it = 0; it < NE / 2048; ++it) {
    const int e0 = it * 2048 + tid * 4;
    const int4 bt = *(const int4*)(batch + e0);
    const bool f[4] = {bt.x == b, bt.y == b, bt.z == b, bt.w == b};
    int rk[4];
    int wcnt = 0;
    #pragma unroll
    for (int u = 0; u < 4; ++u) {
      unsigned long long mk = __ballot(f[u]);
      rk[u] = wcnt + __popcll(mk & lt);
      wcnt += __popcll(mk);
    }
    __syncthreads();
    if (lane == 0) wbase[wid] = wcnt;
    __syncthreads();
    if (tid == 0) {
      int r = running;
      #pragma unroll
      for (int w = 0; w < 8; ++w) { int c = wbase[w]; wbase[w] = r; r += c; }
      running = r;
    }
    __syncthreads();
    const int base = wbase[wid];
    #pragma unroll
    for (int u = 0; u < 4; ++u) {
      const int p = base + rk[u];
      if (f[u] && p < IDX_STRIDE) myidx[p] = e0 + u;
    }
  }
  __syncthreads();
  if (tid == 0) counts[b] = running;
}

// ---------------- segment attention over bucketized index lists
__device__ __forceinline__ float dot_qk(const float* __restrict__ kp, const float qr[32]) {
  float s = 0.f;
  const float4* kp4 = (const float4*)kp;
  #pragma unroll
  for (int j = 0; j < 8; ++j) {
    float4 kv = kp4[j];
    s = fmaf(qr[4 * j + 0], kv.x, s);
    s = fmaf(qr[4 * j + 1], kv.y, s);
    s = fmaf(qr[4 * j + 2], kv.z, s);
    s = fmaf(qr[4 * j + 3], kv.w, s);
  }
  return s;
}

__global__ __launch_bounds__(256) void attn_k(const float* __restrict__ q_ws,
    const float* __restrict__ k_ws, const float* __restrict__ v_ws,
    const int* __restrict__ idx, const int* __restrict__ counts,
    float* __restrict__ attn_out, float* __restrict__ out_ws)
{
  __shared__ float s_sc[IDX_STRIDE];
  __shared__ float s_m[4], s_l[4];
  __shared__ float s_red[4][DKH];
  __shared__ float s_ml[2];

  const int tid = threadIdx.x;
  const int hb = blockIdx.x;        // h*64 + b
  const int h = hb >> 6;
  const int b = hb & 63;
  const int wid = tid >> 6, lane = tid & 63;

  const int count = min(counts[b], IDX_STRIDE);
  const int* __restrict__ myidx = idx + b * IDX_STRIDE;

  float qr[32];
  {
    const float4* qp = (const float4*)(q_ws + (size_t)b * ND + h * DKH);
    #pragma unroll
    for (int j = 0; j < 8; ++j) {
      float4 t = qp[j];
      qr[4 * j + 0] = t.x; qr[4 * j + 1] = t.y;
      qr[4 * j + 2] = t.z; qr[4 * j + 3] = t.w;
    }
  }

  // pass 1: scores, online (m,l), cache in LDS
  float m = -INFINITY, l = 0.f;
  for (int j = tid; j < count; j += 256) {
    const int e = myidx[j];
    const float s = dot_qk(k_ws + (size_t)e * ND + h * DKH, qr);
    s_sc[j] = s;
    const float mn = fmaxf(m, s);
    l = l * __expf(m - mn) + __expf(s - mn);
    m = mn;
  }

  #pragma unroll
  for (int off = 32; off > 0; off >>= 1) {
    float mo = __shfl_xor(m, off);
    float lo = __shfl_xor(l, off);
    float mn = fmaxf(m, mo);
    if (mn == -INFINITY) { l = 0.f; }
    else { l = l * __expf(m - mn) + lo * __expf(mo - mn); }
    m = mn;
  }
  if (lane == 0) { s_m[wid] = m; s_l[wid] = l; }
  __syncthreads();
  if (tid == 0) {
    float mm = -INFINITY, ll = 0.f;
    #pragma unroll
    for (int w = 0; w < 4; ++w) {
      float mo = s_m[w], lo = s_l[w];
      float mn = fmaxf(mm, mo);
      if (mn == -INFINITY) { ll = 0.f; }
      else { ll = ll * __expf(mm - mn) + lo * __expf(mo - mn); }
      mm = mn;
    }
    s_ml[0] = mm;
    s_ml[1] = (ll > 0.f) ? 1.f / ll : 0.f;
  }
  __syncthreads();
  const float m_all = s_ml[0];
  const float inv = s_ml[1];

  // pass 2a: dense zero of this (h,b) attn row (coalesced)
  float* __restrict__ arow = attn_out + (size_t)hb * NE;
  const float4 z4 = {0.f, 0.f, 0.f, 0.f};
  for (int it = 0; it < NE / 1024; ++it)
    *(float4*)(arow + it * 1024 + tid * 4) = z4;
  __syncthreads();

  // pass 2b: scatter the segment's weights (lines L2-hot from zeroing)
  for (int j = tid; j < count; j += 256)
    arow[myidx[j]] = __expf(s_sc[j] - m_all) * inv;

  // pass 3: PV over the index list
  float oa[32];
  #pragma unroll
  for (int d = 0; d < 32; ++d) oa[d] = 0.f;
  for (int j = tid; j < count; j += 256) {
    const int e = myidx[j];
    const float a = __expf(s_sc[j] - m_all) * inv;
    const float4* vp = (const float4*)(v_ws + (size_t)e * ND + h * DKH);
    #pragma unroll
    for (int jj = 0; jj < 8; ++jj) {
      float4 vv = vp[jj];
      oa[4 * jj + 0] = fmaf(a, vv.x, oa[4 * jj + 0]);
      oa[4 * jj + 1] = fmaf(a, vv.y, oa[4 * jj + 1]);
      oa[4 * jj + 2] = fmaf(a, vv.z, oa[4 * jj + 2]);
      oa[4 * jj + 3] = fmaf(a, vv.w, oa[4 * jj + 3]);
    }
  }

  #pragma unroll
  for (int d = 0; d < 32; ++d) {
    #pragma unroll
    for (int off = 32; off > 0; off >>= 1)
      oa[d] += __shfl_down(oa[d], off);
  }
  if (lane == 0) {
    #pragma unroll
    for (int d = 0; d < 32; ++d) s_red[wid][d] = oa[d];
  }
  __syncthreads();
  if (tid < 32) {
    float v = s_red[0][tid] + s_red[1][tid] + s_red[2][tid] + s_red[3][tid];
    out_ws[(size_t)b * ND + h * DKH + tid] = v;
  }
}

extern "C" void kernel_launch(void* const* d_in, const int* in_sizes, int n_in,
                              void* d_out, int out_size, void* d_ws, size_t ws_size,
                              hipStream_t stream)
{
  const float* gq   = (const float*)d_in[0];
  const float* lk   = (const float*)d_in[1];
  const float* lv   = (const float*)d_in[2];
  const int*  batch = (const int*)d_in[3];
  const float* Wq = (const float*)d_in[4];
  const float* bq = (const float*)d_in[5];
  const float* Wk = (const float*)d_in[6];
  const float* bk = (const float*)d_in[7];
  const float* Wv = (const float*)d_in[8];
  const float* bv = (const float*)d_in[9];
  const float* Wo = (const float*)d_in[10];
  const float* bo = (const float*)d_in[11];

  float* xout = (float*)d_out;                          // [64,256]
  float* attn_out = xout + (size_t)NB * ND;             // [H,B,E]

  float* q_ws   = (float*)d_ws;                         // 64*256
  float* out_ws = q_ws + (size_t)NB * ND;               // 64*256
  float* k_ws   = out_ws + (size_t)NB * ND;             // E*256
  float* v_ws   = k_ws + (size_t)NE * ND;               // E*256
  int*   idx    = (int*)(v_ws + (size_t)NE * ND);       // 64*2048
  int*   counts = idx + (size_t)NB * IDX_STRIDE;        // 64

  rowgemm_k<<<NB, ND, 0, stream>>>(gq, Wq, bq, q_ws);
  gemm_bf16_k<<<1024, 256, 0, stream>>>(lk, Wk, bk, k_ws);
  gemm_bf16_k<<<1024, 256, 0, stream>>>(lv, Wv, bv, v_ws);
  bucket_k<<<NB, 512, 0, stream>>>(batch, idx, counts);
  attn_k<<<NH * NB, 256, 0, stream>>>(q_ws, k_ws, v_ws, idx, counts, attn_out, out_ws);
  rowgemm_k<<<NB, ND, 0, stream>>>(out_ws, Wo, bo, xout);
}